// Round 5
// baseline (473.141 us; speedup 1.0000x reference)
//
#include <hip/hip_runtime.h>

#define N_NODES 8192
#define IN_F 256
#define OUT_F 128
#define ALPHA 0.5f
#define JC 4
#define KCHUNK 2048            // N_NODES / JC
#define RK 128                 // k-window per round
#define ROUNDS 16              // KCHUNK / RK (must be even: loop unrolled x2)
#define RSTEPS 4               // 32-k MFMA steps per round

using short8 = __attribute__((ext_vector_type(8))) short;
using f32x4  = __attribute__((ext_vector_type(4))) float;

__device__ __forceinline__ unsigned int f2bf(float f){
  unsigned int u = __float_as_uint(f);
  u += 0x7fffu + ((u >> 16) & 1u);   // RNE
  return u >> 16;
}
__device__ __forceinline__ float bf2f(short s){
  return __uint_as_float(((unsigned int)(unsigned short)s) << 16);
}

// ---------------- K0: fused  h = x@W  ->  {f1, f2, P(bf16 frag-major)} -----
__global__ __launch_bounds__(256) void k_hfp(const float* __restrict__ x,
                                             const float* __restrict__ W,
                                             const float* __restrict__ a,
                                             unsigned short* __restrict__ P,
                                             float* __restrict__ f1,
                                             float* __restrict__ f2){
  __shared__ float xs[16*IN_F];            // 16 KB; reused as hs[16][132]
  const int tid = threadIdx.x;
  const int bx = blockIdx.x;
  const int r0 = bx * 16;
  const float4* xg = (const float4*)(x + (size_t)r0*IN_F);
  float4* xl = (float4*)xs;
  #pragma unroll
  for(int i=0;i<4;i++) xl[tid + i*256] = xg[tid + i*256];
  __syncthreads();
  const int wave = tid >> 6, lane = tid & 63;
  float2 acc[4];
  #pragma unroll
  for(int j=0;j<4;j++){ acc[j].x = 0.f; acc[j].y = 0.f; }
  const float2* Wp = (const float2*)W;
  for(int k4=0;k4<IN_F;k4+=4){
    float4 xq[4];
    #pragma unroll
    for(int j=0;j<4;j++) xq[j] = *(const float4*)&xs[(wave*4+j)*IN_F + k4];
    #pragma unroll
    for(int kk=0;kk<4;kk++){
      float2 wv = Wp[(size_t)(k4+kk)*64 + lane];
      #pragma unroll
      for(int j=0;j<4;j++){
        float xv = kk==0?xq[j].x : kk==1?xq[j].y : kk==2?xq[j].z : xq[j].w;
        acc[j].x += xv*wv.x; acc[j].y += xv*wv.y;
      }
    }
  }
  // ---- f1 = h@a1, f2 = h@a2 from fp32 accumulators ----
  float2 av1 = ((const float2*)a)[lane];
  float2 av2 = ((const float2*)(a + OUT_F))[lane];
  #pragma unroll
  for(int j=0;j<4;j++){
    float s1 = acc[j].x*av1.x + acc[j].y*av1.y;
    float s2 = acc[j].x*av2.x + acc[j].y*av2.y;
    #pragma unroll
    for(int off=32; off; off>>=1){
      s1 += __shfl_down(s1, off);
      s2 += __shfl_down(s2, off);
    }
    if(lane == 0){ f1[r0 + wave*4 + j] = s1; f2[r0 + wave*4 + j] = s2; }
  }
  // ---- pack bf16 fragment-major into P via LDS re-stage ----
  // P short idx ((kb*8+c)*64 + q*16 + n)*8 + t = bf16(h[kb*32+q*8+t][c*16+n])
  __syncthreads();                         // all waves done reading xs
  #pragma unroll
  for(int j=0;j<4;j++) *(float2*)&xs[(wave*4+j)*132 + lane*2] = acc[j];
  __syncthreads();
  const int kb = bx >> 1, half = bx & 1;   // this block = rows [r0, r0+16) = half of kb's 32
  const int c = tid >> 5, ql = (tid >> 4) & 1, n = tid & 15;
  short8 v;
  #pragma unroll
  for(int t=0;t<8;t++) v[t] = (short)f2bf(xs[(ql*8+t)*132 + c*16 + n]);
  *(short8*)(P + ((size_t)((kb*8 + c)*64 + half*32 + ql*16 + n))*8) = v;
}

// ---------------- K1: pipelined fused masked-exp + attn@h ------------------
// grid (JC=4, 128) x 256 thr, 2 blocks/CU. Per round: issue NEXT round's
// B (8 int4, L2) + adj (8 int4, HBM) + f2 loads into the idle register set,
// then ds_write/compute from the CURRENT set. Barriers are raw s_barrier
// with lgkmcnt(0)-only waits (LDS ordering) — the vmcnt(0) drain that
// __syncthreads would emit is gone, so the HBM adj stream stays in flight
// across the MFMA phase. Loop unrolled x2 with named register sets: a
// register copy of a pending load result would force the vmem wait.
__global__ __launch_bounds__(256, 2) void k_attn(const int* __restrict__ adj,
    const unsigned short* __restrict__ P,
    const float* __restrict__ f1, const float* __restrict__ f2,
    float* __restrict__ part, float* __restrict__ denp){
  __shared__ __align__(16) unsigned short Alds[64*RK];   // 16 KB swizzled [row][k]
  __shared__ __align__(16) short Blds[RK*OUT_F];         // 32 KB fragment-major
  __shared__ float f1s[64];
  const int tid = threadIdx.x;
  const int wave = tid >> 6, lane = tid & 63;
  const int m = lane & 15, q = lane >> 4;
  const int jc = blockIdx.x;                 // linear id % 4 -> XCD-spread
  const int r0b = blockIdx.y * 64;
  const int jb = jc * KCHUNK;
  const int kb0 = jc * (KCHUNK/32);
  // staging coords: thread covers rows {i*8+srow}, k-cols [sc0, sc0+4)
  const int srow = tid >> 5;                 // 0..7
  const int sc0  = (tid & 31) * 4;           // 0..124
  const int swz  = ((((sc0 >> 3) ^ srow) << 4) | ((sc0 & 4) << 1));

  if(tid < 64) f1s[tid] = f1[r0b + tid];

  f32x4 acc0[8];
  #pragma unroll
  for(int c=0;c<8;c++) acc0[c] = (f32x4){0,0,0,0};
  float den0 = 0.f;

  const char* Ab = (const char*)Alds;
  char* Aw = (char*)Alds + swz;
  const int mw = m & 7;
  const int rg0 = wave*16 + m;
  int4* Bl4 = (int4*)Blds;
  const char* apbase = (const char*)adj + (((size_t)(r0b + srow)*N_NODES + jb + sc0) << 2);

  __syncthreads();                           // f1s ready (one-time full drain ok)

  // prologue: issue round-0 B + adj + f2 into set A
  int4 bA[8], bB[8], aA[8], aB[8];
  float4 fA, fB;
  {
    const int4* Pb = (const int4*)(P + ((size_t)kb0 << 12));
    #pragma unroll
    for(int i=0;i<8;i++) bA[i] = Pb[i*256 + tid];
    #pragma unroll
    for(int i=0;i<8;i++) aA[i] = *(const int4*)(apbase + ((size_t)i*8*N_NODES << 2));
    fA = *(const float4*)(f2 + jb + sc0);
  }

#define RB(RD, AC, AN, BC, BN, FC, FN)                                          \
  {                                                                             \
    const int rdn = ((RD)+1 < ROUNDS) ? (RD)+1 : (RD);                          \
    const int4* Pbn = (const int4*)(P + ((size_t)(kb0 + rdn*4) << 12));         \
    _Pragma("unroll")                                                           \
    for(int i=0;i<8;i++) BN[i] = Pbn[i*256 + tid];                              \
    const char* apn = apbase + ((size_t)(rdn*RK) << 2);                         \
    _Pragma("unroll")                                                           \
    for(int i=0;i<8;i++) AN[i] = *(const int4*)(apn + ((size_t)i*8*N_NODES << 2)); \
    FN = *(const float4*)(f2 + jb + rdn*RK + sc0);                              \
    _Pragma("unroll")                                                           \
    for(int i=0;i<8;i++) Bl4[i*256 + tid] = BC[i];                              \
    _Pragma("unroll")                                                           \
    for(int i=0;i<8;i++){                                                       \
      int4 av = AC[i];                                                          \
      float f1v = f1s[i*8 + srow];                                              \
      float t0 = f1v + FC.x, t1 = f1v + FC.y, t2 = f1v + FC.z, t3 = f1v + FC.w; \
      t0 = t0 > 0.f ? t0 : ALPHA*t0;  t1 = t1 > 0.f ? t1 : ALPHA*t1;            \
      t2 = t2 > 0.f ? t2 : ALPHA*t2;  t3 = t3 > 0.f ? t3 : ALPHA*t3;            \
      float w0 = av.x > 0 ? __expf(t0) : 0.f;                                   \
      float w1 = av.y > 0 ? __expf(t1) : 0.f;                                   \
      float w2 = av.z > 0 ? __expf(t2) : 0.f;                                   \
      float w3 = av.w > 0 ? __expf(t3) : 0.f;                                   \
      uint2 pk;                                                                 \
      pk.x = f2bf(w0) | (f2bf(w1) << 16);                                       \
      pk.y = f2bf(w2) | (f2bf(w3) << 16);                                       \
      *(uint2*)(Aw + (i*8 + srow)*(RK*2)) = pk;                                 \
    }                                                                           \
    asm volatile("s_waitcnt lgkmcnt(0)" ::: "memory");                          \
    __builtin_amdgcn_s_barrier();                                               \
    _Pragma("unroll")                                                           \
    for(int s=0;s<RSTEPS;s++){                                                  \
      const int gq = ((s*4 + q) ^ mw) << 4;                                     \
      short8 A0 = *(const short8*)(Ab + rg0*(RK*2) + gq);                       \
      _Pragma("unroll")                                                         \
      for(int t=0;t<8;t++) den0 += bf2f(A0[t]);                                 \
      const short8* Bl = (const short8*)Blds + s*512 + lane;                    \
      _Pragma("unroll")                                                         \
      for(int c=0;c<8;c++){                                                     \
        short8 Bf = Bl[c*64];                                                   \
        acc0[c] = __builtin_amdgcn_mfma_f32_16x16x32_bf16(A0, Bf, acc0[c], 0,0,0); \
      }                                                                         \
    }                                                                           \
    __builtin_amdgcn_s_barrier();                                               \
  }

  for(int rd2=0; rd2<ROUNDS; rd2+=2){
    RB(rd2,   aA, aB, bA, bB, fA, fB)
    RB(rd2+1, aB, aA, bB, bA, fB, fA)
  }
#undef RB

  // den: lanes m, m+16, m+32, m+48 hold q-partials of row m
  den0 += __shfl_down(den0, 32); den0 += __shfl_down(den0, 16);
  const int r0w = r0b + wave*16;
  if(lane < 16) denp[(size_t)jc*N_NODES + r0w + lane] = den0;
  // C/D layout: col = c*16 + m, row = q*4 + reg (verified)
  float* pp = part + (size_t)jc*N_NODES*OUT_F;
  #pragma unroll
  for(int c=0;c<8;c++){
    #pragma unroll
    for(int reg=0;reg<4;reg++)
      pp[(size_t)(r0w + q*4 + reg)*OUT_F + c*16 + m] = acc0[c][reg];
  }
}

// ---------------- K2: out = elu(sum(parts)/sum(dens)), float4 ----------------
__global__ __launch_bounds__(256) void k_out(const float* __restrict__ part,
    const float* __restrict__ denp, float* __restrict__ out){
  const int idx = blockIdx.x*256 + threadIdx.x;    // float4 index
  const int r = idx >> 5;                          // (idx*4) >> 7
  float4 v = {0.f,0.f,0.f,0.f};
  float d = 0.f;
  #pragma unroll
  for(int p=0;p<JC;p++){
    float4 pv = *((const float4*)part + (size_t)p*(N_NODES*OUT_F/4) + idx);
    v.x += pv.x; v.y += pv.y; v.z += pv.z; v.w += pv.w;
    d += denp[(size_t)p*N_NODES + r];
  }
  float4 o;
  o.x = v.x/d; o.y = v.y/d; o.z = v.z/d; o.w = v.w/d;
  o.x = o.x>0.f ? o.x : (__expf(o.x)-1.f);
  o.y = o.y>0.f ? o.y : (__expf(o.y)-1.f);
  o.z = o.z>0.f ? o.z : (__expf(o.z)-1.f);
  o.w = o.w>0.f ? o.w : (__expf(o.w)-1.f);
  *((float4*)out + idx) = o;
}

extern "C" void kernel_launch(void* const* d_in, const int* in_sizes, int n_in,
                              void* d_out, int out_size, void* d_ws, size_t ws_size,
                              hipStream_t stream){
  const float* x   = (const float*)d_in[0];
  const int*   adj = (const int*)d_in[1];
  const float* W   = (const float*)d_in[2];
  const float* a   = (const float*)d_in[3];
  char* ws = (char*)d_ws;
  unsigned short* P = (unsigned short*)ws;                 // 2 MiB
  float* f1         = (float*)(ws + (2u<<20));             // 32 KiB
  float* f2         = (float*)(ws + (2u<<20) + (32u<<10)); // 32 KiB
  float* part       = (float*)(ws + (4u<<20));             // 16 MiB
  float* denp       = (float*)(ws + (20u<<20));            // 128 KiB
  float* out        = (float*)d_out;

  k_hfp<<<512, 256, 0, stream>>>(x, W, a, P, f1, f2);
  k_attn<<<dim3(JC,128), 256, 0, stream>>>(adj, P, f1, f2, part, denp);
  k_out<<<(N_NODES*OUT_F)/4/256, 256, 0, stream>>>(part, denp, out);
}

// Round 8
// 418.851 us; speedup vs baseline: 1.1296x; 1.1296x over previous
//
#include <hip/hip_runtime.h>

#define N_NODES 8192
#define IN_F 256
#define OUT_F 128
#define ALPHA 0.5f
#define JC 4
#define KCHUNK 2048            // N_NODES / JC
#define RK 64                  // k-window per round
#define ROUNDS 32              // KCHUNK / RK

using short8 = __attribute__((ext_vector_type(8))) short;
using f32x4  = __attribute__((ext_vector_type(4))) float;

__device__ __forceinline__ unsigned int f2bf(float f){
  unsigned int u = __float_as_uint(f);
  u += 0x7fffu + ((u >> 16) & 1u);   // RNE
  return u >> 16;
}
__device__ __forceinline__ float bf2f(short s){
  return __uint_as_float(((unsigned int)(unsigned short)s) << 16);
}
__device__ __forceinline__ void gll16(const void* g, void* l){
  __builtin_amdgcn_global_load_lds(
      (const __attribute__((address_space(1))) void*)g,
      (__attribute__((address_space(3))) void*)l, 16, 0, 0);
}

// ---------------- K0: fused  h = x@W  ->  {f1, f2, P(bf16 frag-major)} -----
__global__ __launch_bounds__(256) void k_hfp(const float* __restrict__ x,
                                             const float* __restrict__ W,
                                             const float* __restrict__ a,
                                             unsigned short* __restrict__ P,
                                             float* __restrict__ f1,
                                             float* __restrict__ f2){
  __shared__ float xs[16*IN_F];            // 16 KB; reused as hs[16][132]
  const int tid = threadIdx.x;
  const int bx = blockIdx.x;
  const int r0 = bx * 16;
  const float4* xg = (const float4*)(x + (size_t)r0*IN_F);
  float4* xl = (float4*)xs;
  #pragma unroll
  for(int i=0;i<4;i++) xl[tid + i*256] = xg[tid + i*256];
  __syncthreads();
  const int wave = tid >> 6, lane = tid & 63;
  float2 acc[4];
  #pragma unroll
  for(int j=0;j<4;j++){ acc[j].x = 0.f; acc[j].y = 0.f; }
  const float2* Wp = (const float2*)W;
  for(int k4=0;k4<IN_F;k4+=4){
    float4 xq[4];
    #pragma unroll
    for(int j=0;j<4;j++) xq[j] = *(const float4*)&xs[(wave*4+j)*IN_F + k4];
    #pragma unroll
    for(int kk=0;kk<4;kk++){
      float2 wv = Wp[(size_t)(k4+kk)*64 + lane];
      #pragma unroll
      for(int j=0;j<4;j++){
        float xv = kk==0?xq[j].x : kk==1?xq[j].y : kk==2?xq[j].z : xq[j].w;
        acc[j].x += xv*wv.x; acc[j].y += xv*wv.y;
      }
    }
  }
  // ---- f1 = h@a1, f2 = h@a2 from fp32 accumulators ----
  float2 av1 = ((const float2*)a)[lane];
  float2 av2 = ((const float2*)(a + OUT_F))[lane];
  #pragma unroll
  for(int j=0;j<4;j++){
    float s1 = acc[j].x*av1.x + acc[j].y*av1.y;
    float s2 = acc[j].x*av2.x + acc[j].y*av2.y;
    #pragma unroll
    for(int off=32; off; off>>=1){
      s1 += __shfl_down(s1, off);
      s2 += __shfl_down(s2, off);
    }
    if(lane == 0){ f1[r0 + wave*4 + j] = s1; f2[r0 + wave*4 + j] = s2; }
  }
  // ---- pack bf16 fragment-major into P via LDS re-stage ----
  // P short idx ((kb*8+c)*64 + q*16 + n)*8 + t = bf16(h[kb*32+q*8+t][c*16+n])
  __syncthreads();                         // all waves done reading xs
  #pragma unroll
  for(int j=0;j<4;j++) *(float2*)&xs[(wave*4+j)*132 + lane*2] = acc[j];
  __syncthreads();
  const int kb = bx >> 1, half = bx & 1;   // this block = rows [r0, r0+16) = half of kb's 32
  const int c = tid >> 5, ql = (tid >> 4) & 1, n = tid & 15;
  short8 v;
  #pragma unroll
  for(int t=0;t<8;t++) v[t] = (short)f2bf(xs[(ql*8+t)*132 + c*16 + n]);
  *(short8*)(P + ((size_t)((kb*8 + c)*64 + half*32 + ql*16 + n))*8) = v;
}

// ---------------- K1: DMA-pipelined fused masked-exp + attn@h --------------
// grid (JC=4, 128) x 256 thr, 2 blocks/CU, LDS 72 KB.
// Per round: issue 8 global_load_lds (4 adj rows->adjraw[nxt], 4 B->Bbuf[nxt]),
// s_waitcnt vmcnt(8) (waits only PREVIOUS round's DMAs; fresh 8 stay in
// flight through compute), raw s_barrier, then compute: each lane builds
// its MFMA A-fragment in registers from its own 8 adj ints (per-lane layout)
// + 16 MFMA. lgkmcnt(0)+s_barrier closes the round.
// global_load_lds semantics: LDS dest = wave-uniform base + lane*16;
// global SOURCE is per-lane and must carry the lane term explicitly.
// (Round-7 bug: B source was wave-uniform -> 64 copies of 16B. Fixed.)
__global__ __launch_bounds__(256, 2) void k_attn(const int* __restrict__ adj,
    const unsigned short* __restrict__ P,
    const float* __restrict__ f1, const float* __restrict__ f2,
    float* __restrict__ part, float* __restrict__ denp){
  __shared__ __align__(16) int   adjraw[2][64*RK];     // 2 x 16 KB
  __shared__ __align__(16) short Bbuf[2][RK*OUT_F];    // 2 x 16 KB fragment-major
  __shared__ __align__(16) float f2s[KCHUNK];          // 8 KB
  const int tid = threadIdx.x;
  const int wave = tid >> 6, lane = tid & 63;
  const int m = lane & 15, q = lane >> 4;
  const int jc = blockIdx.x;                 // linear id % 4 -> XCD-local P chunk
  const int r0b = blockIdx.y * 64;
  const int jb = jc * KCHUNK;
  const int kb0 = jc * (KCHUNK/32);
  const int r0w = r0b + wave*16;             // this wave's 16 rows

  const float f1v = f1[r0w + m];
  // f2 chunk -> LDS once (8 KB)
  {
    const float4* fsrc = (const float4*)(f2 + jb) + tid*2;
    float4 v0 = fsrc[0], v1 = fsrc[1];
    ((float4*)f2s)[tid*2]     = v0;
    ((float4*)f2s)[tid*2 + 1] = v1;
  }
  f32x4 acc[8];
  #pragma unroll
  for(int c=0;c<8;c++) acc[c] = (f32x4){0,0,0,0};
  float den = 0.f;

  __syncthreads();                           // one-time full drain; f2s visible

  // stage round r into buffer b: 4 adj DMAs (wave-own rows) + 4 B DMAs
  auto stage = [&](int r, int b){
    #pragma unroll
    for(int j=0;j<4;j++){
      const int rl = wave*16 + j*4 + (lane>>4);       // row within block (0..63)
      const int gsw = ((((lane>>1)&7) ^ (rl&7)) << 3) + ((lane&1)<<2); // XOR'd granule, ints
      gll16(adj + (size_t)(r0b + rl)*N_NODES + jb + r*RK + gsw,
            &adjraw[b][(wave*16 + j*4)*RK]);
    }
    #pragma unroll
    for(int j=0;j<4;j++){
      gll16((const char*)P + (((size_t)(kb0 + r*2)) << 13) + wave*4096 + j*1024 + lane*16,
            (char*)Bbuf[b] + wave*4096 + j*1024);
    }
  };

  stage(0, 0);
  for(int rd=0; rd<ROUNDS; rd++){
    const int cur = rd & 1;
    if(rd + 1 < ROUNDS){
      stage(rd + 1, cur ^ 1);
      asm volatile("s_waitcnt vmcnt(8)" ::: "memory");   // prev round's 8 DMAs done
    } else {
      asm volatile("s_waitcnt vmcnt(0)" ::: "memory");   // last round: drain
    }
    __builtin_amdgcn_s_barrier();                         // bufs[cur] ready for all
    #pragma unroll
    for(int s=0;s<2;s++){
      const float* gp = &f2s[rd*RK + s*32 + q*8];         // broadcast per q-group
      float4 g0 = *(const float4*)gp;
      float4 g1 = *(const float4*)(gp + 4);
      const int gpos = (s*4 + q) ^ (m & 7);               // stored granule
      const int4* ap = (const int4*)&adjraw[cur][(wave*16 + m)*RK + gpos*8];
      int4 av0 = ap[0], av1 = ap[1];
      float t0 = f1v + g0.x, t1 = f1v + g0.y, t2 = f1v + g0.z, t3 = f1v + g0.w;
      t0 = t0 > 0.f ? t0 : ALPHA*t0;  t1 = t1 > 0.f ? t1 : ALPHA*t1;
      t2 = t2 > 0.f ? t2 : ALPHA*t2;  t3 = t3 > 0.f ? t3 : ALPHA*t3;
      float w0 = av0.x > 0 ? __expf(t0) : 0.f;
      float w1 = av0.y > 0 ? __expf(t1) : 0.f;
      float w2 = av0.z > 0 ? __expf(t2) : 0.f;
      float w3 = av0.w > 0 ? __expf(t3) : 0.f;
      float t4 = f1v + g1.x, t5 = f1v + g1.y, t6 = f1v + g1.z, t7 = f1v + g1.w;
      t4 = t4 > 0.f ? t4 : ALPHA*t4;  t5 = t5 > 0.f ? t5 : ALPHA*t5;
      t6 = t6 > 0.f ? t6 : ALPHA*t6;  t7 = t7 > 0.f ? t7 : ALPHA*t7;
      float w4 = av1.x > 0 ? __expf(t4) : 0.f;
      float w5 = av1.y > 0 ? __expf(t5) : 0.f;
      float w6 = av1.z > 0 ? __expf(t6) : 0.f;
      float w7 = av1.w > 0 ? __expf(t7) : 0.f;
      uint4 pk;
      pk.x = f2bf(w0) | (f2bf(w1) << 16);
      pk.y = f2bf(w2) | (f2bf(w3) << 16);
      pk.z = f2bf(w4) | (f2bf(w5) << 16);
      pk.w = f2bf(w6) | (f2bf(w7) << 16);
      short8 af = __builtin_bit_cast(short8, pk);
      #pragma unroll
      for(int t=0;t<8;t++) den += bf2f(af[t]);
      #pragma unroll
      for(int c=0;c<8;c++){
        short8 Bf = *(const short8*)&Bbuf[cur][((s*8 + c)*64 + lane)*8];
        acc[c] = __builtin_amdgcn_mfma_f32_16x16x32_bf16(af, Bf, acc[c], 0,0,0);
      }
    }
    asm volatile("s_waitcnt lgkmcnt(0)" ::: "memory");    // LDS reads retired
    __builtin_amdgcn_s_barrier();                         // bufs[cur] free to re-DMA
  }

  // den: lanes m, m+16, m+32, m+48 hold q-partials of row m
  den += __shfl_down(den, 32); den += __shfl_down(den, 16);
  if(lane < 16) denp[(size_t)jc*N_NODES + r0w + lane] = den;
  // C/D layout: col = c*16 + m, row = q*4 + reg (verified)
  float* pp = part + (size_t)jc*N_NODES*OUT_F;
  #pragma unroll
  for(int c=0;c<8;c++){
    #pragma unroll
    for(int reg=0;reg<4;reg++)
      pp[(size_t)(r0w + q*4 + reg)*OUT_F + c*16 + m] = acc[c][reg];
  }
}

// ---------------- K2: out = elu(sum(parts)/sum(dens)), float4 ----------------
__global__ __launch_bounds__(256) void k_out(const float* __restrict__ part,
    const float* __restrict__ denp, float* __restrict__ out){
  const int idx = blockIdx.x*256 + threadIdx.x;    // float4 index
  const int r = idx >> 5;                          // (idx*4) >> 7
  float4 v = {0.f,0.f,0.f,0.f};
  float d = 0.f;
  #pragma unroll
  for(int p=0;p<JC;p++){
    float4 pv = *((const float4*)part + (size_t)p*(N_NODES*OUT_F/4) + idx);
    v.x += pv.x; v.y += pv.y; v.z += pv.z; v.w += pv.w;
    d += denp[(size_t)p*N_NODES + r];
  }
  float4 o;
  o.x = v.x/d; o.y = v.y/d; o.z = v.z/d; o.w = v.w/d;
  o.x = o.x>0.f ? o.x : (__expf(o.x)-1.f);
  o.y = o.y>0.f ? o.y : (__expf(o.y)-1.f);
  o.z = o.z>0.f ? o.z : (__expf(o.z)-1.f);
  o.w = o.w>0.f ? o.w : (__expf(o.w)-1.f);
  *((float4*)out + idx) = o;
}

extern "C" void kernel_launch(void* const* d_in, const int* in_sizes, int n_in,
                              void* d_out, int out_size, void* d_ws, size_t ws_size,
                              hipStream_t stream){
  const float* x   = (const float*)d_in[0];
  const int*   adj = (const int*)d_in[1];
  const float* W   = (const float*)d_in[2];
  const float* a   = (const float*)d_in[3];
  char* ws = (char*)d_ws;
  unsigned short* P = (unsigned short*)ws;                 // 2 MiB
  float* f1         = (float*)(ws + (2u<<20));             // 32 KiB
  float* f2         = (float*)(ws + (2u<<20) + (32u<<10)); // 32 KiB
  float* part       = (float*)(ws + (4u<<20));             // 16 MiB
  float* denp       = (float*)(ws + (20u<<20));            // 128 KiB
  float* out        = (float*)d_out;

  k_hfp<<<512, 256, 0, stream>>>(x, W, a, P, f1, f2);
  k_attn<<<dim3(JC,128), 256, 0, stream>>>(adj, P, f1, f2, part, denp);
  k_out<<<(N_NODES*OUT_F)/4/256, 256, 0, stream>>>(part, denp, out);
}